// Round 23
// baseline (87.988 us; speedup 1.0000x reference)
//
#include <hip/hip_runtime.h>

typedef unsigned short u16;
typedef __attribute__((ext_vector_type(4))) float f32x4;
typedef __attribute__((ext_vector_type(8))) __bf16 bf16x8;
typedef __attribute__((ext_vector_type(8))) unsigned short u16x8;
typedef __attribute__((ext_vector_type(4))) unsigned short u16x4;

#define NEGINF -3.0e38f

// B=2, S=2048, H=1024, NH=16, KVH=4, HD=64
#define BB 2
#define SS 2048
#define HH 1024
#define NHEAD 16
#define KVHEAD 4
#define HD 64
#define BS (BB*SS)          // 4096
#define NQKV 1536           // 1024 + 256 + 256

// log2(e) folded constants: Q prescaled by 0.125*log2e, softmax bias -8*log2e.
#define QSCALE 0.18033688f
#define SMBIAS -11.5415603f

// per-(pair,half) partial slot: 128x64 bf16 acc (4096 u16) + 128 f32 lsum
#define PACC 8192            // u16 elements
#define PSLOTB (8192*2 + 128*4)   // bytes: acc bf16 + lsum f32

__device__ __forceinline__ u16 f2bf(float f) {
  union { float f; unsigned int u; } v; v.f = f;
  unsigned int r = v.u + 0x7FFFu + ((v.u >> 16) & 1u);
  return (u16)(r >> 16);
}
__device__ __forceinline__ float bf2f(u16 h) {
  union { unsigned int u; float f; } v; v.u = ((unsigned int)h) << 16;
  return v.f;
}

typedef const unsigned int __attribute__((address_space(1)))* gp_t;
typedef unsigned int __attribute__((address_space(3)))* lp_t;
__device__ __forceinline__ void gload_lds16(const void* g, void* l) {
  __builtin_amdgcn_global_load_lds((gp_t)g, (lp_t)l, 16, 0, 0);
}

// ---------------- f32 -> bf16 conversion of WEIGHTS only (X fused into QKV GEMM) ----------------
// segments (elem offsets): qw 1048576 | kw 262144 | vw 262144 | ow 1048576
__global__ __launch_bounds__(256) void cvt_all(
    const float* __restrict__ qw, const float* __restrict__ kw,
    const float* __restrict__ vw, const float* __restrict__ ow,
    u16* __restrict__ Wqkv, u16* __restrict__ Wo) {
  long i = ((long)blockIdx.x * 256 + threadIdx.x) * 4;
  const float* src; u16* dst;
  if (i < 1048576L)      { src = qw + i;             dst = Wqkv + i; }
  else if (i < 1310720L) { src = kw + (i - 1048576); dst = Wqkv + i; }
  else if (i < 1572864L) { src = vw + (i - 1310720); dst = Wqkv + i; }
  else                   { src = ow + (i - 1572864); dst = Wo + (i - 1572864); }
  float4 v = *(const float4*)src;
  u16x4 o;
  o.x = f2bf(v.x); o.y = f2bf(v.y); o.z = f2bf(v.z); o.w = f2bf(v.w);
  *(u16x4*)dst = o;
}

// ---------------- GEMM: C[m,n] = sum_k A[m,k]*Bw[n,k] ----------------
// Tile TM(M)x128(N), BK=64, 4 waves each owning (TM/2)x64. XOR-swizzled LDS.
// DOUBLE-BUFFERED single-barrier pipeline (r13).
// EPI=0 (QKV): A is F32 (hidden) — T14 async-split reg-staging (issue f32 loads
// early, cvt+ds_write late, hidden under MFMA); epilogue fuses RMSNorm + RoPE
// for Q/K, V transposed Vt. EPI=1 (O): A bf16 via gload_lds; f32 store to Cf.
template<int EPI, int TM>
__global__ __launch_bounds__(256) void gemm_bt(
    const float* __restrict__ Af, const u16* __restrict__ A,
    const u16* __restrict__ Bw,
    float* __restrict__ Cf,
    u16* __restrict__ Qb, u16* __restrict__ Kb, u16* __restrict__ Vb,
    const float* __restrict__ cosb, const float* __restrict__ sinb,
    const float* __restrict__ qnw, const float* __restrict__ knw,
    int M, int N, int K)
{
  const int AM = TM / 32;            // M-fragments per wave
  __shared__ u16 As[2][TM * 64];
  __shared__ u16 Bs[2][128 * 64];
  const int tid = threadIdx.x;
  const int w = tid >> 6, l = tid & 63;
  const int lg = l >> 4, lc = l & 15;
  const int m0 = blockIdx.y * TM, n0 = blockIdx.x * 128;
  const int wr = (w >> 1) * (TM / 2), wc = (w & 1) * 64;

  const f32x4 vzero = {0.f, 0.f, 0.f, 0.f};
  f32x4 acc[AM][4];
#pragma unroll
  for (int i = 0; i < AM; ++i)
#pragma unroll
    for (int j = 0; j < 4; ++j) acc[i][j] = vzero;

  const u16* Bp = Bw + (size_t)n0 * K;
  const int nk = K >> 6;

  const int arow = tid >> 3, ach = tid & 7;

  // B staging (both EPI): 4 gload_lds issues of 256 lanes x 16B
#define BSTAGE(bufi, kt)                                                         \
  {                                                                              \
    _Pragma("unroll") for (int c = 0; c < 4; ++c) {                              \
      int row = c * 32 + arow;                                                   \
      gload_lds16(Bp + (size_t)row * K + (kt) * 64 + (ach ^ (row & 7)) * 8,      \
                  (char*)Bs[bufi] + c * 4096 + w * 1024);                        \
    }                                                                            \
  }
  // A staging, EPI==1 (bf16 source): AM gload_lds issues
#define ASTAGE1(bufi, kt)                                                        \
  {                                                                              \
    _Pragma("unroll") for (int c = 0; c < AM; ++c) {                             \
      int row = c * 32 + arow;                                                   \
      gload_lds16(A + (size_t)(m0 + row) * K + (kt) * 64 + (ach ^ (row & 7)) * 8,\
                  (char*)As[bufi] + c * 4096 + w * 1024);                        \
    }                                                                            \
  }
  // A staging, EPI==0 (f32 source): loads into regs (issue early)
  f32x4 a4[2][2];   // [chunk][half] — AM==2 for TM=64
#define ALOAD0(kt)                                                               \
  {                                                                              \
    _Pragma("unroll") for (int c = 0; c < 2; ++c) {                              \
      int fc = c * 256 + tid, row = fc >> 3, ch2 = fc & 7;                       \
      const float* src = Af + (size_t)(m0 + row) * K + (kt) * 64 + ((ch2 ^ (row & 7)) * 8); \
      a4[c][0] = *(const f32x4*)src;                                             \
      a4[c][1] = *(const f32x4*)(src + 4);                                       \
    }                                                                            \
  }
  // convert + write late (hidden under MFMA)
#define AWRITE0(bufi)                                                            \
  {                                                                              \
    _Pragma("unroll") for (int c = 0; c < 2; ++c) {                              \
      u16x8 o;                                                                   \
      _Pragma("unroll") for (int j = 0; j < 4; ++j) {                            \
        o[j] = f2bf(a4[c][0][j]);                                                \
        o[4 + j] = f2bf(a4[c][1][j]);                                            \
      }                                                                          \
      *(u16x8*)((char*)As[bufi] + c * 4096 + tid * 16) = o;                      \
    }                                                                            \
  }

  if (EPI == 0) {
    ALOAD0(0)
    AWRITE0(0)
    BSTAGE(0, 0)
  } else {
    ASTAGE1(0, 0)
    BSTAGE(0, 0)
  }
  __syncthreads();   // certify tile 0

  for (int kt = 0; kt < nk; ++kt) {
    const int cur = kt & 1;
    if (kt + 1 < nk) {
      if (EPI == 0) ALOAD0(kt + 1)
      else          ASTAGE1(cur ^ 1, kt + 1)
      BSTAGE(cur ^ 1, kt + 1)
    }

    bf16x8 af[AM][2], bfr[4][2];
#pragma unroll
    for (int i = 0; i < AM; ++i) {
      int row = wr + i * 16 + lc;
#pragma unroll
      for (int c = 0; c < 2; ++c)
        af[i][c] = *(const bf16x8*)&As[cur][row * 64 + (((c * 4 + lg) ^ (lc & 7)) << 3)];
    }
#pragma unroll
    for (int i = 0; i < 4; ++i) {
      int row = wc + i * 16 + lc;
#pragma unroll
      for (int c = 0; c < 2; ++c)
        bfr[i][c] = *(const bf16x8*)&Bs[cur][row * 64 + (((c * 4 + lg) ^ (lc & 7)) << 3)];
    }
    __builtin_amdgcn_s_setprio(1);
#pragma unroll
    for (int c = 0; c < 2; ++c)
#pragma unroll
      for (int am = 0; am < AM; ++am)
#pragma unroll
        for (int bn = 0; bn < 4; ++bn)
          acc[am][bn] = __builtin_amdgcn_mfma_f32_16x16x32_bf16(af[am][c], bfr[bn][c], acc[am][bn], 0, 0, 0);
    __builtin_amdgcn_s_setprio(0);

    if (kt + 1 < nk) {
      if (EPI == 0) AWRITE0(cur ^ 1)   // f32 loads returned during MFMA; write next buf
      __syncthreads();                 // drains B gload + certifies A ds_writes
    }
  }
#undef BSTAGE
#undef ASTAGE1
#undef ALOAD0
#undef AWRITE0

  if (EPI == 1) {
#pragma unroll
    for (int am = 0; am < AM; ++am)
#pragma unroll
      for (int bn = 0; bn < 4; ++bn)
#pragma unroll
        for (int r = 0; r < 4; ++r) {
          int m = m0 + wr + am * 16 + lg * 4 + r;
          int n = n0 + wc + bn * 16 + lc;
          Cf[(size_t)m * N + n] = acc[am][bn][r];
        }
  } else {
    const int nb = n0 + wc;  // 64-aligned: whole wave in one Q/K/V head-slice
    if (nb < 1280) {
      // ---- Q or K head: fused RMSNorm + RoPE ----
      const bool isQ = (nb < 1024);
      const int head = isQ ? (nb >> 6) : ((nb - 1024) >> 6);
      u16* dst = isQ ? (Qb + ((size_t)head * SS) * HD)
                     : (Kb + ((size_t)head * SS) * HD);
      const size_t hstride = (size_t)(isQ ? NHEAD : KVHEAD) * SS * HD;
      const float* wt = isQ ? qnw : knw;
      const float posc = isQ ? QSCALE : 1.0f;
      float wt4[4];
#pragma unroll
      for (int bn = 0; bn < 4; ++bn) wt4[bn] = wt[bn * 16 + lc];
#pragma unroll
      for (int am = 0; am < AM; ++am)
#pragma unroll
        for (int r = 0; r < 4; ++r) {
          int m = m0 + wr + am * 16 + lg * 4 + r;
          int bb = m >> 11, s2 = m & 2047;
          float ss = 0.f;
#pragma unroll
          for (int bn = 0; bn < 4; ++bn) ss += acc[am][bn][r] * acc[am][bn][r];
          ss += __shfl_xor(ss, 1);
          ss += __shfl_xor(ss, 2);
          ss += __shfl_xor(ss, 4);
          ss += __shfl_xor(ss, 8);
          float rs = rsqrtf(ss * (1.0f / 64.0f) + 1e-6f);
          size_t cbase = ((size_t)bb * SS + s2) * HD;
          size_t obase = bb * hstride + (size_t)s2 * HD;
#pragma unroll
          for (int bn = 0; bn < 4; ++bn) {
            int d = bn * 16 + lc;
            float xn = acc[am][bn][r] * rs * wt4[bn];
            float xp = acc[am][bn ^ 2][r] * rs * wt4[bn ^ 2];
            float rot = (bn < 2) ? -xp : xp;
            float o = (xn * cosb[cbase + d] + rot * sinb[cbase + d]) * posc;
            dst[obase + d] = f2bf(o);
          }
        }
    } else {
      // ---- V head: transposed write Vt[b][kh][d][s] ----
      const int kh = (nb - 1280) >> 6;
#pragma unroll
      for (int am = 0; am < AM; ++am)
#pragma unroll
        for (int r = 0; r < 4; ++r) {
          int m = m0 + wr + am * 16 + lg * 4 + r;
          int bb = m >> 11, s2 = m & 2047;
#pragma unroll
          for (int bn = 0; bn < 4; ++bn) {
            int d = bn * 16 + lc;
            Vb[(((size_t)bb * KVHEAD + kh) * HD + d) * SS + s2] = f2bf(acc[am][bn][r]);
          }
        }
    }
  }
}

// ---------------- Flash attention phase 1: SPLIT-KV, equal 17-tile blocks ----------------
// (r18/r22 config — session best.) Static-max softmax (||q||=||k||=8 -> fixed
// max 8, bias in MFMA C-init) makes partial (acc,lsum) ORDER-INDEPENDENT SUMS ->
// exact split-KV. Pair p=(b,h,qt_s): J1=qt_s (L1=2qt_s+2 tiles), J2=15-qt_s.
// Block A (bid<256): all of J1 (finalized in-kernel) + first 17-L1 tiles of J2.
// Block B (bid+256, same CU): last 17 tiles of J2. EVERY block = 17 tiles.
// Partial acc stored BF16 (halves Pw traffic; lsum stays f32).
__global__ __launch_bounds__(256) void attn_kernel(
    const u16* __restrict__ Qb, const u16* __restrict__ Kb,
    const u16* __restrict__ Vt, u16* __restrict__ Ob,
    char* __restrict__ Pw)
{
  __shared__ u16 Ks[2][64 * 64];   // [key][d], 16B-slot XOR-swizzled
  __shared__ u16 Vs[2][64 * 64];   // [d][key], same swizzle

  const int tid = threadIdx.x;
  const int w = tid >> 6, l = tid & 63;
  const int lg = l >> 4, lc = l & 15;

  const int bid = blockIdx.x;
  const int p = bid & 255, half = bid >> 8;
  const int qt_s = p & 7, hb = p >> 3;
  const int h = hb & 15, b = hb >> 4;
  const int qt_l = 15 - qt_s;
  const int L1 = 2 * qt_s + 2;
  const int kvh = h >> 2;

  const u16* Kp = Kb + ((size_t)b * KVHEAD + kvh) * SS * HD;
  const u16* Vp = Vt + ((size_t)b * KVHEAD + kvh) * (size_t)HD * SS;

  const f32x4 vzero = {0.f, 0.f, 0.f, 0.f};
  const f32x4 zbias = {SMBIAS, SMBIAS, SMBIAS, SMBIAS};
  f32x4 acc[2][4];
  float lsum[2] = {0.f, 0.f};
#pragma unroll
  for (int qf = 0; qf < 2; ++qf)
#pragma unroll
    for (int df = 0; df < 4; ++df) acc[qf][df] = vzero;

  // staging geometry: 256 threads x 16B x 4 issues = K-tile + V-tile
  const int srow0 = w * 8 + (l >> 3);
  const int srow1 = srow0 + 32;
  const int sswz = (l >> 3) ^ ((w & 1) << 2);      // (row&7)^((row>>3&1)<<2)
  const int ss0 = (l & 7) ^ sswz;

  // per-lane LDS element offsets for the fragment reads (within one 64*64 tile)
  int ko[8], vo[8];
#pragma unroll
  for (int f = 0; f < 4; ++f) {
    int row = ((lc >> 2) << 3) + ((f & 1) << 2) + (lc & 3) + ((f >> 1) << 5);
    int swz = (((f & 1) << 2) + (lc & 3)) ^ (((lc >> 2) & 1) << 2);
    ko[2 * f]     = row * 64 + ((lg ^ swz) << 3);
    ko[2 * f + 1] = row * 64 + (((4 + lg) ^ swz) << 3);
  }
#pragma unroll
  for (int df = 0; df < 4; ++df) {
    int vrow = 16 * df + lc;
    int vswz = (lc & 7) ^ (((lc >> 3) & 1) << 2);
    vo[2 * df]     = vrow * 64 + ((lg ^ vswz) << 3);
    vo[2 * df + 1] = vrow * 64 + (((4 + lg) ^ vswz) << 3);
  }

#define STAGE(bufi, kvbase)                                                          \
  gload_lds16(Kp + (size_t)((kvbase) + srow0) * HD + ss0 * 8, (char*)Ks[bufi] + w * 1024);        \
  gload_lds16(Kp + (size_t)((kvbase) + srow1) * HD + ss0 * 8, (char*)Ks[bufi] + 4096 + w * 1024); \
  gload_lds16(Vp + (size_t)srow0 * SS + (kvbase) + ss0 * 8, (char*)Vs[bufi] + w * 1024);          \
  gload_lds16(Vp + (size_t)srow1 * SS + (kvbase) + ss0 * 8, (char*)Vs[bufi] + 4096 + w * 1024);

  auto seg = [&](int qt, int lo, int hi, bool fin) {
    const int q0 = qt * 128;
    const u16* Qp = Qb + (((size_t)b * NHEAD + h) * SS + q0 + w * 32) * HD;
    bf16x8 qa[2][2];
#pragma unroll
    for (int qf = 0; qf < 2; ++qf)
#pragma unroll
      for (int c = 0; c < 2; ++c)
        qa[qf][c] = *(const bf16x8*)(Qp + (qf * 16 + lc) * HD + c * 32 + lg * 8);

    STAGE(0, lo * 64)
    __syncthreads();

    for (int t = lo; t < hi; ++t) {
      const int cur = (t - lo) & 1;
      if (t + 1 < hi) { STAGE(cur ^ 1, (t + 1) * 64) }

      const int kv0 = t * 64;
      // wave-uniform skip of fully-masked tiles (wave w covers rows q0+w*32..+31)
      if (kv0 <= q0 + w * 32 + 31) {
        const u16* KsB = Ks[cur];
        const u16* VsB = Vs[cur];

        bf16x8 kb[8], vb[8];
#pragma unroll
        for (int i = 0; i < 8; ++i) kb[i] = *(const bf16x8*)&KsB[ko[i]];
#pragma unroll
        for (int i = 0; i < 8; ++i) vb[i] = *(const bf16x8*)&VsB[vo[i]];

        const bool diag = (kv0 + 63 > q0 + w * 32);
        bf16x8 pa[2][2];
#pragma unroll
        for (int c = 0; c < 2; ++c) {
          f32x4 sv[2][2];   // [qf][fs], f = 2c+fs
#pragma unroll
          for (int fs = 0; fs < 2; ++fs) {
            const int f = 2 * c + fs;
#pragma unroll
            for (int qf = 0; qf < 2; ++qf) {
              f32x4 z = zbias;
              z = __builtin_amdgcn_mfma_f32_16x16x32_bf16(kb[2 * f], qa[qf][0], z, 0, 0, 0);
              z = __builtin_amdgcn_mfma_f32_16x16x32_bf16(kb[2 * f + 1], qa[qf][1], z, 0, 0, 0);
              sv[qf][fs] = z;
            }
          }
          if (diag) {
            const int keyb = kv0 + c * 32 + lg * 8;
#pragma unroll
            for (int qf = 0; qf < 2; ++qf) {
              const int qi = q0 + w * 32 + qf * 16 + lc;
#pragma unroll
              for (int fs = 0; fs < 2; ++fs)
#pragma unroll
                for (int rr = 0; rr < 4; ++rr) {
                  int key = keyb + fs * 4 + rr;
                  if (key > qi) sv[qf][fs][rr] = NEGINF;
                }
            }
          }
#pragma unroll
          for (int qf = 0; qf < 2; ++qf) {
#pragma unroll
            for (int fs = 0; fs < 2; ++fs)
#pragma unroll
              for (int rr = 0; rr < 4; ++rr) {
                float pp = __builtin_amdgcn_exp2f(sv[qf][fs][rr]);
                sv[qf][fs][rr] = pp;
                lsum[qf] += pp;
              }
#pragma unroll
            for (int j = 0; j < 8; ++j)
              pa[qf][c][j] = (__bf16)sv[qf][j >> 2][j & 3];
          }
        }

        // PV
#pragma unroll
        for (int df = 0; df < 4; ++df)
#pragma unroll
          for (int qf = 0; qf < 2; ++qf) {
            acc[qf][df] = __builtin_amdgcn_mfma_f32_16x16x32_bf16(pa[qf][0], vb[2 * df], acc[qf][df], 0, 0, 0);
            acc[qf][df] = __builtin_amdgcn_mfma_f32_16x16x32_bf16(pa[qf][1], vb[2 * df + 1], acc[qf][df], 0, 0, 0);
          }
      }

      __syncthreads();  // certifies STAGE(t+1) + protects LDS across segments
    }

    if (fin) {
      // finalize J1: full rows computed by this block alone
#pragma unroll
      for (int qf = 0; qf < 2; ++qf) {
        float t = lsum[qf];
        t += __shfl_xor(t, 16);
        t += __shfl_xor(t, 32);
#pragma unroll
        for (int rr = 0; rr < 4; ++rr) {
          float dnm = __shfl(t, lg * 4 + rr);
          float inv = 1.0f / dnm;
          int qi = q0 + w * 32 + qf * 16 + lg * 4 + rr;
#pragma unroll
          for (int df = 0; df < 4; ++df)
            Ob[((size_t)b * SS + qi) * (NHEAD * HD) + h * HD + df * 16 + lc] =
                f2bf(acc[qf][df][rr] * inv);
        }
        lsum[qf] = 0.f;
#pragma unroll
        for (int df = 0; df < 4; ++df) acc[qf][df] = vzero;
      }
    }
  };

  if (half == 0) {
    seg(qt_s, 0, L1, true);
    seg(qt_l, 0, 17 - L1, false);
  } else {
    seg(qt_l, 17 - L1, 2 * qt_l + 2, false);
  }
#undef STAGE

  // write J2 partial: acc as bf16 (halved traffic), reduced lsum as f32
  u16* slota = (u16*)(Pw + (size_t)(p * 2 + half) * PSLOTB);
  float* slotl = (float*)(slota + PACC);
#pragma unroll
  for (int qf = 0; qf < 2; ++qf) {
#pragma unroll
    for (int rr = 0; rr < 4; ++rr) {
      int row = w * 32 + qf * 16 + lg * 4 + rr;
#pragma unroll
      for (int df = 0; df < 4; ++df)
        slota[row * 64 + df * 16 + lc] = f2bf(acc[qf][df][rr]);
    }
    float t = lsum[qf];
    t += __shfl_xor(t, 16);
    t += __shfl_xor(t, 32);
    if (l < 16) slotl[w * 32 + qf * 16 + l] = t;
  }
}

// ---------------- attention phase 2: combine split-KV partials ----------------
__global__ __launch_bounds__(256) void attn_combine(
    const char* __restrict__ Pw, u16* __restrict__ Ob)
{
  const int blk = blockIdx.x;         // 0..511
  const int p = blk >> 1, rh = blk & 1;
  const int qt_s = p & 7, hb = p >> 3;
  const int h = hb & 15, b = hb >> 4;
  const int qt_l = 15 - qt_s;
  const u16* Aa = (const u16*)(Pw + (size_t)(p * 2 + 0) * PSLOTB);
  const float* Al = (const float*)(Aa + PACC);
  const u16* Ba = (const u16*)(Pw + (size_t)(p * 2 + 1) * PSLOTB);
  const float* Bl = (const float*)(Ba + PACC);
#pragma unroll
  for (int i = 0; i < 16; ++i) {
    int e = i * 256 + threadIdx.x;    // 0..4095
    int row = rh * 64 + (e >> 6), d = e & 63;
    float s = bf2f(Aa[row * 64 + d]) + bf2f(Ba[row * 64 + d]);
    float dn = Al[row] + Bl[row];
    int qrow = qt_l * 128 + row;
    Ob[((size_t)b * SS + qrow) * (NHEAD * HD) + h * HD + d] = f2bf(s / dn);
  }
}

extern "C" void kernel_launch(void* const* d_in, const int* in_sizes, int n_in,
                              void* d_out, int out_size, void* d_ws, size_t ws_size,
                              hipStream_t stream) {
  const float* hidden = (const float*)d_in[0];
  // d_in[1] = attention_mask: exactly causal, handled analytically
  const float* cosb = (const float*)d_in[2];
  const float* sinb = (const float*)d_in[3];
  const float* qw = (const float*)d_in[4];
  const float* kw = (const float*)d_in[5];
  const float* vw = (const float*)d_in[6];
  const float* ow = (const float*)d_in[7];
  const float* qnw = (const float*)d_in[8];
  const float* knw = (const float*)d_in[9];
  float* out = (float*)d_out;

  u16* Wqkv = (u16*)d_ws;                      // 1536*1024
  u16* Wo   = Wqkv + (size_t)NQKV * HH;        // 1024*1024
  u16* Qb   = Wo + (size_t)HH * HH;            // (B,NH,S,HD)
  u16* Kb   = Qb + (size_t)BB * NHEAD * SS * HD;   // (B,KVH,S,HD)
  u16* Vb   = Kb + (size_t)BB * KVHEAD * SS * HD;  // (B,KVH,HD,S) transposed
  u16* Ab   = Vb + (size_t)BB * KVHEAD * SS * HD;  // 4096*1024
  char* Pw  = (char*)(Ab + (size_t)BS * HH);       // 512 slots x (16KB acc + 512B lsum) ~ 8.6 MB

  // weights-only conversion (X conversion fused into QKV A-staging)
  cvt_all<<<2560, 256, 0, stream>>>(qw, kw, vw, ow, Wqkv, Wo);

  // QKV projection: A = f32 hidden (fused cvt), 64x128 tiles, 768 blocks = 3/CU
  gemm_bt<0, 64><<<dim3(NQKV / 128, BS / 64), 256, 0, stream>>>(
      hidden, nullptr, Wqkv, nullptr, Qb, Kb, Vb, cosb, sinb, qnw, knw, BS, NQKV, HH);

  // attention: 2-way split-KV phase 1 (512 equal 17-tile blocks) + combine
  attn_kernel<<<512, 256, 0, stream>>>(Qb, Kb, Vb, Ab, Pw);
  attn_combine<<<512, 256, 0, stream>>>(Pw, Ab);

  // O projection: A bf16 via gload_lds, 64x128 tiles, 512 blocks = 2/CU
  gemm_bt<1, 64><<<dim3(HH / 128, BS / 64), 256, 0, stream>>>(
      nullptr, Ab, Wo, out, nullptr, nullptr, nullptr, nullptr, nullptr, nullptr, nullptr, BS, HH, HH);
}

// Round 24
// 84.385 us; speedup vs baseline: 1.0427x; 1.0427x over previous
//
#include <hip/hip_runtime.h>

typedef unsigned short u16;
typedef __attribute__((ext_vector_type(4))) float f32x4;
typedef __attribute__((ext_vector_type(8))) __bf16 bf16x8;
typedef __attribute__((ext_vector_type(8))) unsigned short u16x8;
typedef __attribute__((ext_vector_type(4))) unsigned short u16x4;

#define NEGINF -3.0e38f

// B=2, S=2048, H=1024, NH=16, KVH=4, HD=64
#define BB 2
#define SS 2048
#define HH 1024
#define NHEAD 16
#define KVHEAD 4
#define HD 64
#define BS (BB*SS)          // 4096
#define NQKV 1536           // 1024 + 256 + 256

// log2(e) folded constants: Q prescaled by 0.125*log2e, softmax bias -8*log2e.
#define QSCALE 0.18033688f
#define SMBIAS -11.5415603f

// per-(pair,half) partial slot: 128x64 bf16 acc (4096 u16) + 128 f32 lsum
#define PACC 8192            // u16 elements
#define PSLOTB (8192*2 + 128*4)   // bytes: acc bf16 + lsum f32

__device__ __forceinline__ u16 f2bf(float f) {
  union { float f; unsigned int u; } v; v.f = f;
  unsigned int r = v.u + 0x7FFFu + ((v.u >> 16) & 1u);
  return (u16)(r >> 16);
}
__device__ __forceinline__ float bf2f(u16 h) {
  union { unsigned int u; float f; } v; v.u = ((unsigned int)h) << 16;
  return v.f;
}

typedef const unsigned int __attribute__((address_space(1)))* gp_t;
typedef unsigned int __attribute__((address_space(3)))* lp_t;
__device__ __forceinline__ void gload_lds16(const void* g, void* l) {
  __builtin_amdgcn_global_load_lds((gp_t)g, (lp_t)l, 16, 0, 0);
}

// ---------------- fused f32 -> bf16 conversion of all inputs ----------------
__global__ __launch_bounds__(256) void cvt_all(
    const float* __restrict__ h, const float* __restrict__ qw,
    const float* __restrict__ kw, const float* __restrict__ vw,
    const float* __restrict__ ow,
    u16* __restrict__ Xb, u16* __restrict__ Wqkv, u16* __restrict__ Wo) {
  long i = ((long)blockIdx.x * 256 + threadIdx.x) * 4;
  const float* src; u16* dst;
  if (i < 4194304L)      { src = h  + i;             dst = Xb   + i; }
  else if (i < 5242880L) { src = qw + (i - 4194304); dst = Wqkv + (i - 4194304); }
  else if (i < 5505024L) { src = kw + (i - 5242880); dst = Wqkv + (i - 4194304); }
  else if (i < 5767168L) { src = vw + (i - 5505024); dst = Wqkv + (i - 4194304); }
  else                   { src = ow + (i - 5767168); dst = Wo   + (i - 5767168); }
  float4 v = *(const float4*)src;
  u16x4 o;
  o.x = f2bf(v.x); o.y = f2bf(v.y); o.z = f2bf(v.z); o.w = f2bf(v.w);
  *(u16x4*)dst = o;
}

// ---------------- GEMM: C[m,n] = sum_k A[m,k]*Bw[n,k] (both bf16) ----------------
// Tile TM(M)x128(N), BK=64, 4 waves each owning (TM/2)x64. XOR-swizzled LDS.
// DOUBLE-BUFFERED single-barrier pipeline (r13). TM=64 both (r18-best: grid
// overlap beats per-wave MFMA:read ratio). EPI=0 (QKV): epilogue fuses RMSNorm
// + RoPE for Q/K; V transposed Vt. EPI=1 (O): f32 store to Cf.
template<int EPI, int TM>
__global__ __launch_bounds__(256) void gemm_bt(
    const u16* __restrict__ A, const u16* __restrict__ Bw,
    float* __restrict__ Cf,
    u16* __restrict__ Qb, u16* __restrict__ Kb, u16* __restrict__ Vb,
    const float* __restrict__ cosb, const float* __restrict__ sinb,
    const float* __restrict__ qnw, const float* __restrict__ knw,
    int M, int N, int K)
{
  const int AM = TM / 32;            // M-fragments per wave
  __shared__ u16 As[2][TM * 64];
  __shared__ u16 Bs[2][128 * 64];
  const int tid = threadIdx.x;
  const int w = tid >> 6, l = tid & 63;
  const int lg = l >> 4, lc = l & 15;
  const int m0 = blockIdx.y * TM, n0 = blockIdx.x * 128;
  const int wr = (w >> 1) * (TM / 2), wc = (w & 1) * 64;

  const f32x4 vzero = {0.f, 0.f, 0.f, 0.f};
  f32x4 acc[AM][4];
#pragma unroll
  for (int i = 0; i < AM; ++i)
#pragma unroll
    for (int j = 0; j < 4; ++j) acc[i][j] = vzero;

  const u16* Ap = A + (size_t)m0 * K;
  const u16* Bp = Bw + (size_t)n0 * K;
  const int nk = K >> 6;

  const int arow = tid >> 3, ach = tid & 7;

#define GSTAGE(bufi, kt)                                                         \
  {                                                                              \
    _Pragma("unroll") for (int c = 0; c < AM; ++c) {                             \
      int row = c * 32 + arow;                                                   \
      gload_lds16(Ap + (size_t)row * K + (kt) * 64 + (ach ^ (row & 7)) * 8,      \
                  (char*)As[bufi] + c * 4096 + w * 1024);                        \
    }                                                                            \
    _Pragma("unroll") for (int c = 0; c < 4; ++c) {                              \
      int row = c * 32 + arow;                                                   \
      gload_lds16(Bp + (size_t)row * K + (kt) * 64 + (ach ^ (row & 7)) * 8,      \
                  (char*)Bs[bufi] + c * 4096 + w * 1024);                        \
    }                                                                            \
  }

  GSTAGE(0, 0)
  __syncthreads();   // certify tile 0

  for (int kt = 0; kt < nk; ++kt) {
    const int cur = kt & 1;
    if (kt + 1 < nk) GSTAGE(cur ^ 1, kt + 1)

    bf16x8 af[AM][2], bfr[4][2];
#pragma unroll
    for (int i = 0; i < AM; ++i) {
      int row = wr + i * 16 + lc;
#pragma unroll
      for (int c = 0; c < 2; ++c)
        af[i][c] = *(const bf16x8*)&As[cur][row * 64 + (((c * 4 + lg) ^ (lc & 7)) << 3)];
    }
#pragma unroll
    for (int i = 0; i < 4; ++i) {
      int row = wc + i * 16 + lc;
#pragma unroll
      for (int c = 0; c < 2; ++c)
        bfr[i][c] = *(const bf16x8*)&Bs[cur][row * 64 + (((c * 4 + lg) ^ (lc & 7)) << 3)];
    }
    __builtin_amdgcn_s_setprio(1);
#pragma unroll
    for (int c = 0; c < 2; ++c)
#pragma unroll
      for (int am = 0; am < AM; ++am)
#pragma unroll
        for (int bn = 0; bn < 4; ++bn)
          acc[am][bn] = __builtin_amdgcn_mfma_f32_16x16x32_bf16(af[am][c], bfr[bn][c], acc[am][bn], 0, 0, 0);
    __builtin_amdgcn_s_setprio(0);

    if (kt + 1 < nk) __syncthreads();  // drains STAGE(kt+1) — hidden under compute
  }
#undef GSTAGE

  if (EPI == 1) {
#pragma unroll
    for (int am = 0; am < AM; ++am)
#pragma unroll
      for (int bn = 0; bn < 4; ++bn)
#pragma unroll
        for (int r = 0; r < 4; ++r) {
          int m = m0 + wr + am * 16 + lg * 4 + r;
          int n = n0 + wc + bn * 16 + lc;
          Cf[(size_t)m * N + n] = acc[am][bn][r];
        }
  } else {
    const int nb = n0 + wc;  // 64-aligned: whole wave in one Q/K/V head-slice
    if (nb < 1280) {
      // ---- Q or K head: fused RMSNorm + RoPE ----
      const bool isQ = (nb < 1024);
      const int head = isQ ? (nb >> 6) : ((nb - 1024) >> 6);
      u16* dst = isQ ? (Qb + ((size_t)head * SS) * HD)
                     : (Kb + ((size_t)head * SS) * HD);
      const size_t hstride = (size_t)(isQ ? NHEAD : KVHEAD) * SS * HD;
      const float* wt = isQ ? qnw : knw;
      const float posc = isQ ? QSCALE : 1.0f;
      float wt4[4];
#pragma unroll
      for (int bn = 0; bn < 4; ++bn) wt4[bn] = wt[bn * 16 + lc];
#pragma unroll
      for (int am = 0; am < AM; ++am)
#pragma unroll
        for (int r = 0; r < 4; ++r) {
          int m = m0 + wr + am * 16 + lg * 4 + r;
          int bb = m >> 11, s2 = m & 2047;
          float ss = 0.f;
#pragma unroll
          for (int bn = 0; bn < 4; ++bn) ss += acc[am][bn][r] * acc[am][bn][r];
          ss += __shfl_xor(ss, 1);
          ss += __shfl_xor(ss, 2);
          ss += __shfl_xor(ss, 4);
          ss += __shfl_xor(ss, 8);
          float rs = rsqrtf(ss * (1.0f / 64.0f) + 1e-6f);
          size_t cbase = ((size_t)bb * SS + s2) * HD;
          size_t obase = bb * hstride + (size_t)s2 * HD;
#pragma unroll
          for (int bn = 0; bn < 4; ++bn) {
            int d = bn * 16 + lc;
            float xn = acc[am][bn][r] * rs * wt4[bn];
            float xp = acc[am][bn ^ 2][r] * rs * wt4[bn ^ 2];
            float rot = (bn < 2) ? -xp : xp;
            float o = (xn * cosb[cbase + d] + rot * sinb[cbase + d]) * posc;
            dst[obase + d] = f2bf(o);
          }
        }
    } else {
      // ---- V head: transposed write Vt[b][kh][d][s] ----
      const int kh = (nb - 1280) >> 6;
#pragma unroll
      for (int am = 0; am < AM; ++am)
#pragma unroll
        for (int r = 0; r < 4; ++r) {
          int m = m0 + wr + am * 16 + lg * 4 + r;
          int bb = m >> 11, s2 = m & 2047;
#pragma unroll
          for (int bn = 0; bn < 4; ++bn) {
            int d = bn * 16 + lc;
            Vb[(((size_t)bb * KVHEAD + kh) * HD + d) * SS + s2] = f2bf(acc[am][bn][r]);
          }
        }
    }
  }
}

// ---------------- Flash attention phase 1: SPLIT-KV, equal 17-tile blocks ----------------
// (r18 config — session best.) Static-max softmax (||q||=||k||=8 -> fixed max 8,
// bias in MFMA C-init) makes partial (acc,lsum) ORDER-INDEPENDENT SUMS -> exact
// split-KV. Pair p=(b,h,qt_s): J1=qt_s (L1=2qt_s+2 tiles), J2=15-qt_s. Block A
// (bid<256): all of J1 (finalized in-kernel) + first 17-L1 tiles of J2 (below
// diagonal). Block B (bid+256, same CU by round-robin): last 17 tiles of J2.
// EVERY block = exactly 17 tiles -> 2 equal co-resident blocks per CU.
// Partial acc stored BF16 (halves Pw traffic; lsum stays f32).
__global__ __launch_bounds__(256) void attn_kernel(
    const u16* __restrict__ Qb, const u16* __restrict__ Kb,
    const u16* __restrict__ Vt, u16* __restrict__ Ob,
    char* __restrict__ Pw)
{
  __shared__ u16 Ks[2][64 * 64];   // [key][d], 16B-slot XOR-swizzled
  __shared__ u16 Vs[2][64 * 64];   // [d][key], same swizzle

  const int tid = threadIdx.x;
  const int w = tid >> 6, l = tid & 63;
  const int lg = l >> 4, lc = l & 15;

  const int bid = blockIdx.x;
  const int p = bid & 255, half = bid >> 8;
  const int qt_s = p & 7, hb = p >> 3;
  const int h = hb & 15, b = hb >> 4;
  const int qt_l = 15 - qt_s;
  const int L1 = 2 * qt_s + 2;
  const int kvh = h >> 2;

  const u16* Kp = Kb + ((size_t)b * KVHEAD + kvh) * SS * HD;
  const u16* Vp = Vt + ((size_t)b * KVHEAD + kvh) * (size_t)HD * SS;

  const f32x4 vzero = {0.f, 0.f, 0.f, 0.f};
  const f32x4 zbias = {SMBIAS, SMBIAS, SMBIAS, SMBIAS};
  f32x4 acc[2][4];
  float lsum[2] = {0.f, 0.f};
#pragma unroll
  for (int qf = 0; qf < 2; ++qf)
#pragma unroll
    for (int df = 0; df < 4; ++df) acc[qf][df] = vzero;

  // staging geometry: 256 threads x 16B x 4 issues = K-tile + V-tile
  const int srow0 = w * 8 + (l >> 3);
  const int srow1 = srow0 + 32;
  const int sswz = (l >> 3) ^ ((w & 1) << 2);      // (row&7)^((row>>3&1)<<2)
  const int ss0 = (l & 7) ^ sswz;

  // per-lane LDS element offsets for the fragment reads (within one 64*64 tile)
  int ko[8], vo[8];
#pragma unroll
  for (int f = 0; f < 4; ++f) {
    int row = ((lc >> 2) << 3) + ((f & 1) << 2) + (lc & 3) + ((f >> 1) << 5);
    int swz = (((f & 1) << 2) + (lc & 3)) ^ (((lc >> 2) & 1) << 2);
    ko[2 * f]     = row * 64 + ((lg ^ swz) << 3);
    ko[2 * f + 1] = row * 64 + (((4 + lg) ^ swz) << 3);
  }
#pragma unroll
  for (int df = 0; df < 4; ++df) {
    int vrow = 16 * df + lc;
    int vswz = (lc & 7) ^ (((lc >> 3) & 1) << 2);
    vo[2 * df]     = vrow * 64 + ((lg ^ vswz) << 3);
    vo[2 * df + 1] = vrow * 64 + (((4 + lg) ^ vswz) << 3);
  }

#define STAGE(bufi, kvbase)                                                          \
  gload_lds16(Kp + (size_t)((kvbase) + srow0) * HD + ss0 * 8, (char*)Ks[bufi] + w * 1024);        \
  gload_lds16(Kp + (size_t)((kvbase) + srow1) * HD + ss0 * 8, (char*)Ks[bufi] + 4096 + w * 1024); \
  gload_lds16(Vp + (size_t)srow0 * SS + (kvbase) + ss0 * 8, (char*)Vs[bufi] + w * 1024);          \
  gload_lds16(Vp + (size_t)srow1 * SS + (kvbase) + ss0 * 8, (char*)Vs[bufi] + 4096 + w * 1024);

  auto seg = [&](int qt, int lo, int hi, bool fin) {
    const int q0 = qt * 128;
    const u16* Qp = Qb + (((size_t)b * NHEAD + h) * SS + q0 + w * 32) * HD;
    bf16x8 qa[2][2];
#pragma unroll
    for (int qf = 0; qf < 2; ++qf)
#pragma unroll
      for (int c = 0; c < 2; ++c)
        qa[qf][c] = *(const bf16x8*)(Qp + (qf * 16 + lc) * HD + c * 32 + lg * 8);

    STAGE(0, lo * 64)
    __syncthreads();

    for (int t = lo; t < hi; ++t) {
      const int cur = (t - lo) & 1;
      if (t + 1 < hi) { STAGE(cur ^ 1, (t + 1) * 64) }

      const int kv0 = t * 64;
      // wave-uniform skip of fully-masked tiles (wave w covers rows q0+w*32..+31)
      if (kv0 <= q0 + w * 32 + 31) {
        const u16* KsB = Ks[cur];
        const u16* VsB = Vs[cur];

        bf16x8 kb[8], vb[8];
#pragma unroll
        for (int i = 0; i < 8; ++i) kb[i] = *(const bf16x8*)&KsB[ko[i]];
#pragma unroll
        for (int i = 0; i < 8; ++i) vb[i] = *(const bf16x8*)&VsB[vo[i]];

        const bool diag = (kv0 + 63 > q0 + w * 32);
        bf16x8 pa[2][2];
#pragma unroll
        for (int c = 0; c < 2; ++c) {
          f32x4 sv[2][2];   // [qf][fs], f = 2c+fs
#pragma unroll
          for (int fs = 0; fs < 2; ++fs) {
            const int f = 2 * c + fs;
#pragma unroll
            for (int qf = 0; qf < 2; ++qf) {
              f32x4 z = zbias;
              z = __builtin_amdgcn_mfma_f32_16x16x32_bf16(kb[2 * f], qa[qf][0], z, 0, 0, 0);
              z = __builtin_amdgcn_mfma_f32_16x16x32_bf16(kb[2 * f + 1], qa[qf][1], z, 0, 0, 0);
              sv[qf][fs] = z;
            }
          }
          if (diag) {
            const int keyb = kv0 + c * 32 + lg * 8;
#pragma unroll
            for (int qf = 0; qf < 2; ++qf) {
              const int qi = q0 + w * 32 + qf * 16 + lc;
#pragma unroll
              for (int fs = 0; fs < 2; ++fs)
#pragma unroll
                for (int rr = 0; rr < 4; ++rr) {
                  int key = keyb + fs * 4 + rr;
                  if (key > qi) sv[qf][fs][rr] = NEGINF;
                }
            }
          }
#pragma unroll
          for (int qf = 0; qf < 2; ++qf) {
#pragma unroll
            for (int fs = 0; fs < 2; ++fs)
#pragma unroll
              for (int rr = 0; rr < 4; ++rr) {
                float pp = __builtin_amdgcn_exp2f(sv[qf][fs][rr]);
                sv[qf][fs][rr] = pp;
                lsum[qf] += pp;
              }
#pragma unroll
            for (int j = 0; j < 8; ++j)
              pa[qf][c][j] = (__bf16)sv[qf][j >> 2][j & 3];
          }
        }

        // PV
#pragma unroll
        for (int df = 0; df < 4; ++df)
#pragma unroll
          for (int qf = 0; qf < 2; ++qf) {
            acc[qf][df] = __builtin_amdgcn_mfma_f32_16x16x32_bf16(pa[qf][0], vb[2 * df], acc[qf][df], 0, 0, 0);
            acc[qf][df] = __builtin_amdgcn_mfma_f32_16x16x32_bf16(pa[qf][1], vb[2 * df + 1], acc[qf][df], 0, 0, 0);
          }
      }

      __syncthreads();  // certifies STAGE(t+1) + protects LDS across segments
    }

    if (fin) {
      // finalize J1: full rows computed by this block alone
#pragma unroll
      for (int qf = 0; qf < 2; ++qf) {
        float t = lsum[qf];
        t += __shfl_xor(t, 16);
        t += __shfl_xor(t, 32);
#pragma unroll
        for (int rr = 0; rr < 4; ++rr) {
          float dnm = __shfl(t, lg * 4 + rr);
          float inv = 1.0f / dnm;
          int qi = q0 + w * 32 + qf * 16 + lg * 4 + rr;
#pragma unroll
          for (int df = 0; df < 4; ++df)
            Ob[((size_t)b * SS + qi) * (NHEAD * HD) + h * HD + df * 16 + lc] =
                f2bf(acc[qf][df][rr] * inv);
        }
        lsum[qf] = 0.f;
#pragma unroll
        for (int df = 0; df < 4; ++df) acc[qf][df] = vzero;
      }
    }
  };

  if (half == 0) {
    seg(qt_s, 0, L1, true);
    seg(qt_l, 0, 17 - L1, false);
  } else {
    seg(qt_l, 17 - L1, 2 * qt_l + 2, false);
  }
#undef STAGE

  // write J2 partial: acc as bf16 (halved traffic), reduced lsum as f32
  u16* slota = (u16*)(Pw + (size_t)(p * 2 + half) * PSLOTB);
  float* slotl = (float*)(slota + PACC);
#pragma unroll
  for (int qf = 0; qf < 2; ++qf) {
#pragma unroll
    for (int rr = 0; rr < 4; ++rr) {
      int row = w * 32 + qf * 16 + lg * 4 + rr;
#pragma unroll
      for (int df = 0; df < 4; ++df)
        slota[row * 64 + df * 16 + lc] = f2bf(acc[qf][df][rr]);
    }
    float t = lsum[qf];
    t += __shfl_xor(t, 16);
    t += __shfl_xor(t, 32);
    if (l < 16) slotl[w * 32 + qf * 16 + l] = t;
  }
}

// ---------------- attention phase 2: combine split-KV partials ----------------
__global__ __launch_bounds__(256) void attn_combine(
    const char* __restrict__ Pw, u16* __restrict__ Ob)
{
  const int blk = blockIdx.x;         // 0..511
  const int p = blk >> 1, rh = blk & 1;
  const int qt_s = p & 7, hb = p >> 3;
  const int h = hb & 15, b = hb >> 4;
  const int qt_l = 15 - qt_s;
  const u16* Aa = (const u16*)(Pw + (size_t)(p * 2 + 0) * PSLOTB);
  const float* Al = (const float*)(Aa + PACC);
  const u16* Ba = (const u16*)(Pw + (size_t)(p * 2 + 1) * PSLOTB);
  const float* Bl = (const float*)(Ba + PACC);
#pragma unroll
  for (int i = 0; i < 16; ++i) {
    int e = i * 256 + threadIdx.x;    // 0..4095
    int row = rh * 64 + (e >> 6), d = e & 63;
    float s = bf2f(Aa[row * 64 + d]) + bf2f(Ba[row * 64 + d]);
    float dn = Al[row] + Bl[row];
    int qrow = qt_l * 128 + row;
    Ob[((size_t)b * SS + qrow) * (NHEAD * HD) + h * HD + d] = f2bf(s / dn);
  }
}

extern "C" void kernel_launch(void* const* d_in, const int* in_sizes, int n_in,
                              void* d_out, int out_size, void* d_ws, size_t ws_size,
                              hipStream_t stream) {
  const float* hidden = (const float*)d_in[0];
  // d_in[1] = attention_mask: exactly causal, handled analytically
  const float* cosb = (const float*)d_in[2];
  const float* sinb = (const float*)d_in[3];
  const float* qw = (const float*)d_in[4];
  const float* kw = (const float*)d_in[5];
  const float* vw = (const float*)d_in[6];
  const float* ow = (const float*)d_in[7];
  const float* qnw = (const float*)d_in[8];
  const float* knw = (const float*)d_in[9];
  float* out = (float*)d_out;

  u16* Xb   = (u16*)d_ws;                      // 4096*1024
  u16* Wqkv = Xb + (size_t)BS * HH;            // 1536*1024
  u16* Wo   = Wqkv + (size_t)NQKV * HH;        // 1024*1024
  u16* Qb   = Wo + (size_t)HH * HH;            // (B,NH,S,HD)
  u16* Kb   = Qb + (size_t)BB * NHEAD * SS * HD;   // (B,KVH,S,HD)
  u16* Vb   = Kb + (size_t)BB * KVHEAD * SS * HD;  // (B,KVH,HD,S) transposed
  u16* Ab   = Vb + (size_t)BB * KVHEAD * SS * HD;  // 4096*1024
  char* Pw  = (char*)(Ab + (size_t)BS * HH);       // 512 slots x (16KB acc + 512B lsum) ~ 8.6 MB

  cvt_all<<<6656, 256, 0, stream>>>(hidden, qw, kw, vw, ow, Xb, Wqkv, Wo);

  // QKV projection: 64x128 tiles, 768 blocks = 3/CU exact (r18-best config)
  gemm_bt<0, 64><<<dim3(NQKV / 128, BS / 64), 256, 0, stream>>>(
      Xb, Wqkv, nullptr, Qb, Kb, Vb, cosb, sinb, qnw, knw, BS, NQKV, HH);

  // attention: 2-way split-KV phase 1 (512 equal 17-tile blocks) + combine
  attn_kernel<<<512, 256, 0, stream>>>(Qb, Kb, Vb, Ab, Pw);
  attn_combine<<<512, 256, 0, stream>>>(Pw, Ab);

  // O projection: 64x128 tiles, 512 blocks = 2/CU exact
  gemm_bt<1, 64><<<dim3(HH / 128, BS / 64), 256, 0, stream>>>(
      Ab, Wo, out, nullptr, nullptr, nullptr, nullptr, nullptr, nullptr, nullptr, BS, HH, HH);
}